// Round 1
// baseline (566.321 us; speedup 1.0000x reference)
//
#include <hip/hip_runtime.h>
#include <cmath>

typedef unsigned short u16;
typedef __attribute__((ext_vector_type(8))) short bf16x8;
typedef __attribute__((ext_vector_type(4))) float f32x4;

#define MFMA(a,b,c) __builtin_amdgcn_mfma_f32_16x16x32_bf16((a),(b),(c),0,0,0)

__device__ __forceinline__ float bf2f(u16 u){ return __uint_as_float(((unsigned)u)<<16); }
__device__ __forceinline__ u16 f2bf(float f){
  unsigned x = __float_as_uint(f);
  return (u16)((x + 0x7FFFu + ((x>>16)&1u)) >> 16);
}

// ---------- prep: cast+transpose weights to bf16 ----------
// w1 (E,D,H) f32 -> w1t[e][h][d] bf16
__global__ void k_prep_w1t(const float* __restrict__ w1, u16* __restrict__ w1t){
  int idx = blockIdx.x*256 + threadIdx.x;        // (e*512+h)*256 + d
  int d = idx & 255; int h = (idx >> 8) & 511; int e = idx >> 17;
  w1t[idx] = f2bf(w1[(e*256 + d)*512 + h]);
}
// w2 (E,H,D) f32 -> w2t[e][d][h] bf16
__global__ void k_prep_w2t(const float* __restrict__ w2, u16* __restrict__ w2t){
  int idx = blockIdx.x*256 + threadIdx.x;        // (e*256+d)*512 + h
  int h = idx & 511; int d = (idx >> 9) & 255; int e = idx >> 17;
  w2t[idx] = f2bf(w2[(e*512 + h)*256 + d]);
}
// rw1 (261,256): first 256 rows transposed to [j][d] hi/lo bf16; rows 256..260 + rb1
// folded into per-batch bias reg_bias[b][j].
__global__ void k_prep_rw1(const float* __restrict__ rw1, const float* __restrict__ rb1,
                           const float* __restrict__ regime,
                           u16* __restrict__ rwh, u16* __restrict__ rwl,
                           float* __restrict__ regb){
  int idx = blockIdx.x*256 + threadIdx.x;  // 65536 + 2048 total
  if (idx < 65536){
    int dd = idx & 255, j = idx >> 8;
    float w = rw1[dd*256 + j];
    u16 hi = f2bf(w);
    rwh[idx] = hi;
    rwl[idx] = f2bf(w - bf2f(hi));
  } else {
    int i = idx - 65536; int j = i & 255, b = i >> 8;
    float v = rb1[j];
    #pragma unroll
    for (int r=0;r<5;++r) v += regime[b*5+r]*rw1[(256+r)*256 + j];
    regb[b*256 + j] = v;
  }
}

// ---------- LayerNorm: x -> xn hi/lo bf16 (wave per token) ----------
__global__ __launch_bounds__(256) void k_ln(const float* __restrict__ x,
        const float* __restrict__ g, const float* __restrict__ bta,
        u16* __restrict__ xh, u16* __restrict__ xl){
  int wv = threadIdx.x >> 6, lane = threadIdx.x & 63;
  int t = blockIdx.x*4 + wv;
  float4 v = ((const float4*)(x + (size_t)t*256))[lane];
  float s  = v.x+v.y+v.z+v.w;
  float ss = v.x*v.x+v.y*v.y+v.z*v.z+v.w*v.w;
  #pragma unroll
  for (int m=32;m>=1;m>>=1){ s += __shfl_xor(s,m); ss += __shfl_xor(ss,m); }
  float mu  = s*(1.f/256.f);
  float var = ss*(1.f/256.f) - mu*mu;
  float inv = 1.f / sqrtf(var + 1e-5f);
  float4 gv = ((const float4*)g)[lane];
  float4 bv = ((const float4*)bta)[lane];
  float xv[4] = {v.x,v.y,v.z,v.w};
  float gg[4] = {gv.x,gv.y,gv.z,gv.w};
  float bb[4] = {bv.x,bv.y,bv.z,bv.w};
  u16 hh[4], ll[4];
  #pragma unroll
  for (int q=0;q<4;++q){
    float xn = (xv[q]-mu)*inv*gg[q] + bb[q];
    u16 h = f2bf(xn);
    hh[q] = h;
    ll[q] = f2bf(xn - bf2f(h));
  }
  ((ushort4*)(xh + (size_t)t*256))[lane] = make_ushort4(hh[0],hh[1],hh[2],hh[3]);
  ((ushort4*)(xl + (size_t)t*256))[lane] = make_ushort4(ll[0],ll[1],ll[2],ll[3]);
}

// ---------- router GEMM (hi/lo split MFMA): hidden = silu(xn@rw1[:256] + reg_bias) ----------
__global__ __launch_bounds__(256,1) void k_router(const u16* __restrict__ xh, const u16* __restrict__ xl,
        const u16* __restrict__ rwh, const u16* __restrict__ rwl,
        const float* __restrict__ regb, float* __restrict__ hid){
  __shared__ u16 ah[64*264];
  __shared__ u16 al[64*264];
  __shared__ u16 bh[256*40];
  __shared__ u16 bl[256*40];
  int tid = threadIdx.x;
  int lane = tid & 63, wv = tid >> 6;
  int lr = lane & 15, lg = lane >> 4;
  int tb = blockIdx.x * 64;
  for (int c = tid; c < 2048; c += 256){
    int r = c >> 5, cc = c & 31;
    *(uint4*)(&ah[r*264 + cc*8]) = *(const uint4*)(xh + (size_t)(tb+r)*256 + cc*8);
    *(uint4*)(&al[r*264 + cc*8]) = *(const uint4*)(xl + (size_t)(tb+r)*256 + cc*8);
  }
  __syncthreads();
  f32x4 acc[4][4];
  #pragma unroll
  for (int mf=0;mf<4;++mf)
    #pragma unroll
    for (int nf=0;nf<4;++nf) acc[mf][nf] = (f32x4){0.f,0.f,0.f,0.f};

  for (int kt=0; kt<8; ++kt){
    if (kt) __syncthreads();
    {
      const uint4* sh = (const uint4*)(rwh + tid*256 + kt*32);
      const uint4* sl = (const uint4*)(rwl + tid*256 + kt*32);
      uint4* dh = (uint4*)(&bh[tid*40]);
      uint4* dl = (uint4*)(&bl[tid*40]);
      dh[0]=sh[0]; dh[1]=sh[1]; dh[2]=sh[2]; dh[3]=sh[3];
      dl[0]=sl[0]; dl[1]=sl[1]; dl[2]=sl[2]; dl[3]=sl[3];
    }
    __syncthreads();
    bf16x8 af[4], alf[4];
    #pragma unroll
    for (int mf=0;mf<4;++mf){
      af[mf]  = *(const bf16x8*)(&ah[(mf*16+lr)*264 + kt*32 + lg*8]);
      alf[mf] = *(const bf16x8*)(&al[(mf*16+lr)*264 + kt*32 + lg*8]);
    }
    #pragma unroll
    for (int nf=0;nf<4;++nf){
      int n = wv*64 + nf*16 + lr;
      bf16x8 bhf = *(const bf16x8*)(&bh[n*40 + lg*8]);
      bf16x8 blf = *(const bf16x8*)(&bl[n*40 + lg*8]);
      #pragma unroll
      for (int mf=0;mf<4;++mf){
        acc[mf][nf] = MFMA(af[mf],  bhf, acc[mf][nf]);
        acc[mf][nf] = MFMA(alf[mf], bhf, acc[mf][nf]);
        acc[mf][nf] = MFMA(af[mf],  blf, acc[mf][nf]);
      }
    }
  }
  int b = tb >> 12;
  #pragma unroll
  for (int mf=0;mf<4;++mf)
    #pragma unroll
    for (int nf=0;nf<4;++nf){
      int j = wv*64 + nf*16 + lr;
      float rbv = regb[b*256 + j];
      #pragma unroll
      for (int r=0;r<4;++r){
        int t = tb + mf*16 + lg*4 + r;
        float v = acc[mf][nf][r] + rbv;
        hid[(size_t)t*256 + j] = v/(1.f+expf(-v));
      }
    }
}

// ---------- logits + top2 + gate weights + aux partials (thread per token) ----------
__global__ __launch_bounds__(256) void k_logits(const float* __restrict__ hid,
        const float* __restrict__ rw2, const float* __restrict__ rb2,
        float* __restrict__ selw, float* __restrict__ partials){
  __shared__ float psum[6], pcnt[6];
  if (threadIdx.x < 6){ psum[threadIdx.x]=0.f; pcnt[threadIdx.x]=0.f; }
  __syncthreads();
  int t = blockIdx.x*256 + threadIdx.x;
  float lgv[6];
  #pragma unroll
  for (int e=0;e<6;++e) lgv[e] = rb2[e];
  const float4* hp = (const float4*)(hid + (size_t)t*256);
  for (int jj=0;jj<64;++jj){
    float4 h4 = hp[jj];
    float hv[4] = {h4.x,h4.y,h4.z,h4.w};
    #pragma unroll
    for (int q=0;q<4;++q){
      int j = jj*4+q;
      #pragma unroll
      for (int e=0;e<6;++e) lgv[e] += hv[q]*rw2[j*6+e];
    }
  }
  int i0=0; float v0=lgv[0];
  #pragma unroll
  for (int e=1;e<6;++e) if (lgv[e] > v0){ v0=lgv[e]; i0=e; }
  int i1=-1; float v1=-1e30f;
  #pragma unroll
  for (int e=0;e<6;++e) if (e!=i0 && lgv[e] > v1){ v1=lgv[e]; i1=e; }
  float ex = expf(v1-v0);
  float w0 = 1.f/(1.f+ex), w1 = ex/(1.f+ex);
  #pragma unroll
  for (int e=0;e<6;++e) selw[(size_t)t*6+e] = (e==i0)? w0 : (e==i1)? w1 : 0.f;
  float ps=0.f, p[6];
  #pragma unroll
  for (int e=0;e<6;++e){ p[e]=expf(lgv[e]-v0); ps+=p[e]; }
  float rinv = 1.f/ps;
  #pragma unroll
  for (int e=0;e<6;++e) atomicAdd(&psum[e], p[e]*rinv);
  atomicAdd(&pcnt[i0], 1.f);
  __syncthreads();
  if (threadIdx.x < 6){
    partials[blockIdx.x*12 + threadIdx.x] = psum[threadIdx.x];
    partials[blockIdx.x*12 + 6 + threadIdx.x] = pcnt[threadIdx.x];
  }
}

__global__ void k_aux(const float* __restrict__ partials, float* __restrict__ outp){
  __shared__ float a[12];
  int tid = threadIdx.x;
  if (tid < 12){ float s=0.f; for (int b2=0;b2<128;++b2) s += partials[b2*12+tid]; a[tid]=s; }
  __syncthreads();
  if (tid==0){
    float aux=0.f;
    for (int e=0;e<6;++e) aux += a[e]*a[6+e];
    aux *= 0.01f*6.f/(32768.f*32768.f);
    outp[8388608] = aux;
  }
}

// ---------- fused all-expert MLP + weighted combine + residual ----------
__global__ __launch_bounds__(512,1) void k_experts(const u16* __restrict__ xh,
        const u16* __restrict__ w1t, const u16* __restrict__ w2t,
        const float* __restrict__ b1g, const float* __restrict__ b2g,
        const float* __restrict__ selw, const float* __restrict__ xg,
        float* __restrict__ outp){
  __shared__ u16 xs[64*264];
  __shared__ u16 hs[64*520];
  __shared__ u16 bt[512*40];
  __shared__ float wsl[64*6];
  int tid = threadIdx.x;
  int lane = tid & 63, wv = tid >> 6;
  int lr = lane & 15, lg = lane >> 4;
  int wm = wv >> 2, wn = wv & 3;
  int tb = blockIdx.x * 64;
  for (int c = tid; c < 2048; c += 512){
    int r = c >> 5, cc = c & 31;
    *(uint4*)(&xs[r*264 + cc*8]) = *(const uint4*)(xh + (size_t)(tb+r)*256 + cc*8);
  }
  if (tid < 384) wsl[tid] = selw[(size_t)tb*6 + tid];
  __syncthreads();

  f32x4 oacc[2][4];
  #pragma unroll
  for (int mf=0;mf<2;++mf)
    #pragma unroll
    for (int nf=0;nf<4;++nf) oacc[mf][nf] = (f32x4){0.f,0.f,0.f,0.f};

  for (int e=0;e<6;++e){
    // ---- GEMM1: h = silu(xn @ w1[e] + b1[e])  (M=64,N=512,K=256) ----
    f32x4 acc1[2][8];
    #pragma unroll
    for (int mf=0;mf<2;++mf)
      #pragma unroll
      for (int nf=0;nf<8;++nf) acc1[mf][nf] = (f32x4){0.f,0.f,0.f,0.f};
    for (int kt=0;kt<8;++kt){
      __syncthreads();
      {
        const uint4* src = (const uint4*)(w1t + (size_t)((e*512+tid)*256 + kt*32));
        uint4* dst = (uint4*)(&bt[tid*40]);
        dst[0]=src[0]; dst[1]=src[1]; dst[2]=src[2]; dst[3]=src[3];
      }
      __syncthreads();
      bf16x8 a0 = *(const bf16x8*)(&xs[(wm*32+lr)*264 + kt*32 + lg*8]);
      bf16x8 a1 = *(const bf16x8*)(&xs[(wm*32+16+lr)*264 + kt*32 + lg*8]);
      #pragma unroll
      for (int nf=0;nf<8;++nf){
        bf16x8 bb = *(const bf16x8*)(&bt[(wn*128+nf*16+lr)*40 + lg*8]);
        acc1[0][nf] = MFMA(a0,bb,acc1[0][nf]);
        acc1[1][nf] = MFMA(a1,bb,acc1[1][nf]);
      }
    }
    #pragma unroll
    for (int mf=0;mf<2;++mf)
      #pragma unroll
      for (int nf=0;nf<8;++nf){
        int n = wn*128+nf*16+lr;
        float b1v = b1g[e*512+n];
        #pragma unroll
        for (int r=0;r<4;++r){
          int m = wm*32+mf*16+lg*4+r;
          float v = acc1[mf][nf][r] + b1v;
          hs[m*520+n] = f2bf(v/(1.f+expf(-v)));
        }
      }
    __syncthreads();
    // ---- GEMM2: eo = h @ w2[e]  (M=64,N=256,K=512) ----
    f32x4 acc2[2][4];
    #pragma unroll
    for (int mf=0;mf<2;++mf)
      #pragma unroll
      for (int nf=0;nf<4;++nf) acc2[mf][nf] = (f32x4){0.f,0.f,0.f,0.f};
    for (int kt=0;kt<16;++kt){
      __syncthreads();
      {
        int row = tid>>1, half = tid&1;
        const uint4* src = (const uint4*)(w2t + (size_t)((e*256+row)*512 + kt*32 + half*16));
        uint4* dst = (uint4*)(&bt[row*40 + half*16]);
        dst[0]=src[0]; dst[1]=src[1];
      }
      __syncthreads();
      bf16x8 a0 = *(const bf16x8*)(&hs[(wm*32+lr)*520 + kt*32 + lg*8]);
      bf16x8 a1 = *(const bf16x8*)(&hs[(wm*32+16+lr)*520 + kt*32 + lg*8]);
      #pragma unroll
      for (int nf=0;nf<4;++nf){
        bf16x8 bb = *(const bf16x8*)(&bt[(wn*64+nf*16+lr)*40 + lg*8]);
        acc2[0][nf] = MFMA(a0,bb,acc2[0][nf]);
        acc2[1][nf] = MFMA(a1,bb,acc2[1][nf]);
      }
    }
    float wvv[2][4];
    #pragma unroll
    for (int mf=0;mf<2;++mf)
      #pragma unroll
      for (int r=0;r<4;++r)
        wvv[mf][r] = wsl[(wm*32+mf*16+lg*4+r)*6 + e];
    #pragma unroll
    for (int nf=0;nf<4;++nf){
      int n = wn*64+nf*16+lr;
      float b2v = b2g[e*256+n];
      #pragma unroll
      for (int mf=0;mf<2;++mf)
        #pragma unroll
        for (int r=0;r<4;++r)
          oacc[mf][nf][r] += wvv[mf][r]*(acc2[mf][nf][r] + b2v);
    }
  }
  #pragma unroll
  for (int mf=0;mf<2;++mf)
    #pragma unroll
    for (int nf=0;nf<4;++nf)
      #pragma unroll
      for (int r=0;r<4;++r){
        int t = tb + wm*32+mf*16+lg*4+r;
        int d = wn*64+nf*16+lr;
        outp[(size_t)t*256+d] = xg[(size_t)t*256+d] + oacc[mf][nf][r];
      }
}

extern "C" void kernel_launch(void* const* d_in, const int* in_sizes, int n_in,
                              void* d_out, int out_size, void* d_ws, size_t ws_size,
                              hipStream_t stream){
  const float* x      = (const float*)d_in[0];
  const float* regime = (const float*)d_in[1];
  const float* ln_g   = (const float*)d_in[2];
  const float* ln_b   = (const float*)d_in[3];
  const float* w1     = (const float*)d_in[4];
  const float* b1     = (const float*)d_in[5];
  const float* w2     = (const float*)d_in[6];
  const float* b2     = (const float*)d_in[7];
  const float* rw1    = (const float*)d_in[8];
  const float* rb1    = (const float*)d_in[9];
  const float* rw2    = (const float*)d_in[10];
  const float* rb2    = (const float*)d_in[11];
  float* outp = (float*)d_out;
  char* ws = (char*)d_ws;

  u16*   w1t  = (u16*)(ws + 0);
  u16*   w2t  = (u16*)(ws + 1572864);
  u16*   rwh  = (u16*)(ws + 3145728);
  u16*   rwl  = (u16*)(ws + 3276800);
  float* regb = (float*)(ws + 3407872);
  u16*   xh   = (u16*)(ws + 3416064);
  u16*   xl   = (u16*)(ws + 20193280);
  float* hid  = (float*)(ws + 36970496);
  float* selw = (float*)(ws + 70524928);
  float* part = (float*)(ws + 71311360);

  k_prep_w1t<<<3072,256,0,stream>>>(w1, w1t);
  k_prep_w2t<<<3072,256,0,stream>>>(w2, w2t);
  k_prep_rw1<<<264,256,0,stream>>>(rw1, rb1, regime, rwh, rwl, regb);
  k_ln<<<8192,256,0,stream>>>(x, ln_g, ln_b, xh, xl);
  k_router<<<512,256,0,stream>>>(xh, xl, rwh, rwl, regb, hid);
  k_logits<<<128,256,0,stream>>>(hid, rw2, rb2, selw, part);
  k_aux<<<1,64,0,stream>>>(part, outp);
  k_experts<<<512,512,0,stream>>>(xh, w1t, w2t, b1, b2, selw, x, outp);
}

// Round 3
// 332.587 us; speedup vs baseline: 1.7028x; 1.7028x over previous
//
#include <hip/hip_runtime.h>
#include <cmath>

typedef unsigned short u16;
typedef __attribute__((ext_vector_type(8))) short bf16x8;
typedef __attribute__((ext_vector_type(4))) float f32x4;

#define MFMA(a,b,c) __builtin_amdgcn_mfma_f32_16x16x32_bf16((a),(b),(c),0,0,0)

__device__ __forceinline__ float bf2f(u16 u){ return __uint_as_float(((unsigned)u)<<16); }
__device__ __forceinline__ u16 f2bf(float f){
  unsigned x = __float_as_uint(f);
  return (u16)((x + 0x7FFFu + ((x>>16)&1u)) >> 16);
}

// ---------- prep: LDS-tiled transpose f32 [R][C] -> bf16 [C][R] for w1 and w2 ----------
__global__ __launch_bounds__(256) void k_transpose(const float* __restrict__ w1,
        const float* __restrict__ w2, u16* __restrict__ w1t, u16* __restrict__ w2t){
  __shared__ u16 t[64][66];
  int b = blockIdx.x;
  const float* src; u16* dst; int R, C, tr, tc;
  if (b < 192){            // w1: per-expert src (D=256 x H=512) -> w1t[h][d]
    int e = b >> 5, tl = b & 31;
    R = 256; C = 512;
    src = w1 + (size_t)e*131072; dst = w1t + (size_t)e*131072;
    tr = (tl >> 3) << 6; tc = (tl & 7) << 6;
  } else {                 // w2: per-expert src (H=512 x D=256) -> w2t[d][h]
    int bb = b - 192;
    int e = bb >> 5, tl = bb & 31;
    R = 512; C = 256;
    src = w2 + (size_t)e*131072; dst = w2t + (size_t)e*131072;
    tr = (tl >> 2) << 6; tc = (tl & 3) << 6;
  }
  int c0 = threadIdx.x & 63, r0 = threadIdx.x >> 6;
  #pragma unroll
  for (int i=0;i<16;++i){
    int r = r0 + i*4;
    t[c0][r] = f2bf(src[(size_t)(tr+r)*C + tc + c0]);   // coalesced read along C
  }
  __syncthreads();
  #pragma unroll
  for (int i=0;i<16;++i){
    int cc = r0 + i*4;
    dst[(size_t)(tc+cc)*R + tr + c0] = t[cc][c0];       // coalesced write along R
  }
}

// rw1 (261,256): first 256 rows -> [j][d] hi/lo bf16; rows 256..260 + rb1 folded into regb[b][j].
__global__ void k_prep_rw1(const float* __restrict__ rw1, const float* __restrict__ rb1,
                           const float* __restrict__ regime,
                           u16* __restrict__ rwh, u16* __restrict__ rwl,
                           float* __restrict__ regb){
  int idx = blockIdx.x*256 + threadIdx.x;  // 65536 + 2048 total
  if (idx < 65536){
    int dd = idx & 255, j = idx >> 8;
    float w = rw1[dd*256 + j];
    u16 hi = f2bf(w);
    rwh[idx] = hi;
    rwl[idx] = f2bf(w - bf2f(hi));
  } else {
    int i = idx - 65536; int j = i & 255, b = i >> 8;
    float v = rb1[j];
    #pragma unroll
    for (int r=0;r<5;++r) v += regime[b*5+r]*rw1[(256+r)*256 + j];
    regb[b*256 + j] = v;
  }
}

// ---------- LayerNorm: x -> xn hi/lo bf16 (wave per token) ----------
__global__ __launch_bounds__(256) void k_ln(const float* __restrict__ x,
        const float* __restrict__ g, const float* __restrict__ bta,
        u16* __restrict__ xh, u16* __restrict__ xl){
  int wv = threadIdx.x >> 6, lane = threadIdx.x & 63;
  int t = blockIdx.x*4 + wv;
  float4 v = ((const float4*)(x + (size_t)t*256))[lane];
  float s  = v.x+v.y+v.z+v.w;
  float ss = v.x*v.x+v.y*v.y+v.z*v.z+v.w*v.w;
  #pragma unroll
  for (int m=32;m>=1;m>>=1){ s += __shfl_xor(s,m); ss += __shfl_xor(ss,m); }
  float mu  = s*(1.f/256.f);
  float var = ss*(1.f/256.f) - mu*mu;
  float inv = 1.f / sqrtf(var + 1e-5f);
  float4 gv = ((const float4*)g)[lane];
  float4 bv = ((const float4*)bta)[lane];
  float xv[4] = {v.x,v.y,v.z,v.w};
  float gg[4] = {gv.x,gv.y,gv.z,gv.w};
  float bb[4] = {bv.x,bv.y,bv.z,bv.w};
  u16 hh[4], ll[4];
  #pragma unroll
  for (int q=0;q<4;++q){
    float xn = (xv[q]-mu)*inv*gg[q] + bb[q];
    u16 h = f2bf(xn);
    hh[q] = h;
    ll[q] = f2bf(xn - bf2f(h));
  }
  ((ushort4*)(xh + (size_t)t*256))[lane] = make_ushort4(hh[0],hh[1],hh[2],hh[3]);
  ((ushort4*)(xl + (size_t)t*256))[lane] = make_ushort4(ll[0],ll[1],ll[2],ll[3]);
}

// ---------- router GEMM (hi/lo MFMA, weight frags direct from L2, no K-loop barriers) ----------
__global__ __launch_bounds__(256,2) void k_router(const u16* __restrict__ xh, const u16* __restrict__ xl,
        const u16* __restrict__ rwh, const u16* __restrict__ rwl,
        const float* __restrict__ regb, float* __restrict__ hid){
  __shared__ u16 ash[64*264];
  __shared__ u16 asl[64*264];
  int tid = threadIdx.x;
  int lane = tid & 63, wv = tid >> 6;
  int lr = lane & 15, lg = lane >> 4;
  int tb = blockIdx.x * 64;
  for (int c = tid; c < 2048; c += 256){
    int r = c >> 5, cc = c & 31;
    *(uint4*)(&ash[r*264 + cc*8]) = *(const uint4*)(xh + (size_t)(tb+r)*256 + cc*8);
    *(uint4*)(&asl[r*264 + cc*8]) = *(const uint4*)(xl + (size_t)(tb+r)*256 + cc*8);
  }
  __syncthreads();
  f32x4 acc[4][4];
  #pragma unroll
  for (int mf=0;mf<4;++mf)
    #pragma unroll
    for (int nf=0;nf<4;++nf) acc[mf][nf] = (f32x4){0.f,0.f,0.f,0.f};

  const u16* bhb = rwh + (size_t)wv*64*256;
  const u16* blb = rwl + (size_t)wv*64*256;
  #pragma unroll
  for (int kt=0;kt<8;++kt){
    bf16x8 ah[4], al[4], bh[4], bl[4];
    #pragma unroll
    for (int nf=0;nf<4;++nf){
      bh[nf] = *(const bf16x8*)(bhb + (size_t)(nf*16+lr)*256 + kt*32 + lg*8);
      bl[nf] = *(const bf16x8*)(blb + (size_t)(nf*16+lr)*256 + kt*32 + lg*8);
    }
    #pragma unroll
    for (int mf=0;mf<4;++mf){
      ah[mf] = *(const bf16x8*)(&ash[(mf*16+lr)*264 + kt*32 + lg*8]);
      al[mf] = *(const bf16x8*)(&asl[(mf*16+lr)*264 + kt*32 + lg*8]);
    }
    #pragma unroll
    for (int mf=0;mf<4;++mf)
      #pragma unroll
      for (int nf=0;nf<4;++nf){
        acc[mf][nf] = MFMA(ah[mf], bh[nf], acc[mf][nf]);
        acc[mf][nf] = MFMA(al[mf], bh[nf], acc[mf][nf]);
        acc[mf][nf] = MFMA(ah[mf], bl[nf], acc[mf][nf]);
      }
  }
  int b = tb >> 12;
  #pragma unroll
  for (int mf=0;mf<4;++mf)
    #pragma unroll
    for (int nf=0;nf<4;++nf){
      int j = wv*64 + nf*16 + lr;
      float rbv = regb[b*256 + j];
      #pragma unroll
      for (int r=0;r<4;++r){
        int t = tb + mf*16 + lg*4 + r;
        float v = acc[mf][nf][r] + rbv;
        hid[(size_t)t*256 + j] = v/(1.f+__expf(-v));
      }
    }
}

// ---------- logits + top2 + gates + aux partials (16-lane group per token, coalesced) ----------
__global__ __launch_bounds__(256) void k_logits(const float* __restrict__ hid,
        const float* __restrict__ rw2, const float* __restrict__ rb2,
        float* __restrict__ selw, float* __restrict__ partials){
  __shared__ float psum[6], pcnt[6];
  int tid = threadIdx.x;
  if (tid < 6){ psum[tid]=0.f; pcnt[tid]=0.f; }
  __syncthreads();
  int lane = tid & 63;
  int lr = lane & 15, lg = lane >> 4;
  int t = blockIdx.x*16 + (tid>>6)*4 + lg;
  float lacc[6] = {0.f,0.f,0.f,0.f,0.f,0.f};
  const float4* hp = (const float4*)(hid + (size_t)t*256);
  #pragma unroll
  for (int p=0;p<4;++p){
    float4 h4 = hp[p*16 + lr];
    float hv[4] = {h4.x,h4.y,h4.z,h4.w};
    int j0 = (p*16+lr)*4;
    #pragma unroll
    for (int q=0;q<4;++q)
      #pragma unroll
      for (int e=0;e<6;++e) lacc[e] += hv[q]*rw2[(j0+q)*6+e];
  }
  #pragma unroll
  for (int m=1;m<16;m<<=1)
    #pragma unroll
    for (int e=0;e<6;++e) lacc[e] += __shfl_xor(lacc[e], m);
  if (lr == 0){
    float lgv[6];
    #pragma unroll
    for (int e=0;e<6;++e) lgv[e] = lacc[e] + rb2[e];
    int i0=0; float v0=lgv[0];
    #pragma unroll
    for (int e=1;e<6;++e) if (lgv[e] > v0){ v0=lgv[e]; i0=e; }
    int i1=-1; float v1=-1e30f;
    #pragma unroll
    for (int e=0;e<6;++e) if (e!=i0 && lgv[e] > v1){ v1=lgv[e]; i1=e; }
    float ex = expf(v1-v0);
    float w0 = 1.f/(1.f+ex), w1 = ex/(1.f+ex);
    #pragma unroll
    for (int e=0;e<6;++e) selw[(size_t)t*6+e] = (e==i0)? w0 : (e==i1)? w1 : 0.f;
    float ps=0.f, p[6];
    #pragma unroll
    for (int e=0;e<6;++e){ p[e]=expf(lgv[e]-v0); ps+=p[e]; }
    float rinv = 1.f/ps;
    #pragma unroll
    for (int e=0;e<6;++e) atomicAdd(&psum[e], p[e]*rinv);
    atomicAdd(&pcnt[i0], 1.f);
  }
  __syncthreads();
  if (tid < 6){
    partials[blockIdx.x*12 + tid] = psum[tid];
    partials[blockIdx.x*12 + 6 + tid] = pcnt[tid];
  }
}

__global__ __launch_bounds__(256) void k_aux(const float* __restrict__ partials, float* __restrict__ outp){
  __shared__ float a[12];
  int tid = threadIdx.x;
  if (tid < 12) a[tid] = 0.f;
  __syncthreads();
  int col = tid & 15, seg = tid >> 4;
  if (col < 12){
    float s = 0.f;
    for (int i=seg; i<2048; i+=16) s += partials[i*12+col];
    atomicAdd(&a[col], s);
  }
  __syncthreads();
  if (tid==0){
    float aux=0.f;
    #pragma unroll
    for (int e=0;e<6;++e) aux += a[e]*a[6+e];
    aux *= 0.01f*6.f/(32768.f*32768.f);
    outp[8388608] = aux;
  }
}

// ---------- fused all-expert MLP: weight frags direct from L2, swapped GEMM1, hs in LDS ----------
__global__ __launch_bounds__(256,2) void k_experts(const u16* __restrict__ xh,
        const u16* __restrict__ w1t, const u16* __restrict__ w2t,
        const float* __restrict__ b1g, const float* __restrict__ b2g,
        const float* __restrict__ selw, const float* __restrict__ xg,
        float* __restrict__ outp){
  __shared__ u16 xs[64*264];
  __shared__ u16 hs[64*264];
  __shared__ float wsl[64*6];
  int tid = threadIdx.x;                    // 256 threads = 4 waves
  int lane = tid & 63, wv = tid >> 6;
  int lr = lane & 15, lg = lane >> 4;
  int tb = blockIdx.x * 64;

  for (int c = tid; c < 2048; c += 256){
    int r = c >> 5, cc = c & 31;
    *(uint4*)(&xs[r*264 + cc*8]) = *(const uint4*)(xh + (size_t)(tb+r)*256 + cc*8);
  }
  for (int i = tid; i < 384; i += 256)      // FIX: block has 256 threads, need 384 loads
    wsl[i] = selw[(size_t)tb*6 + i];
  __syncthreads();

  f32x4 oacc[4][4];                          // [token-frag][d-frag]
  #pragma unroll
  for (int tf=0;tf<4;++tf)
    #pragma unroll
    for (int df=0;df<4;++df) oacc[tf][df] = (f32x4){0.f,0.f,0.f,0.f};

  for (int e=0;e<6;++e){
    #pragma unroll
    for (int hb=0; hb<2; ++hb){
      // ---- GEMM1 swapped: acc1[hf][tf] = w1[h-rows] x xs[token-rows], K=256, no barriers ----
      f32x4 acc1[4][4];
      #pragma unroll
      for (int hf=0;hf<4;++hf)
        #pragma unroll
        for (int tf=0;tf<4;++tf) acc1[hf][tf] = (f32x4){0.f,0.f,0.f,0.f};
      const u16* w1b = w1t + ((size_t)e*512 + hb*256 + wv*64)*256;
      #pragma unroll
      for (int kt=0; kt<8; ++kt){
        bf16x8 af[4], bxf[4];
        #pragma unroll
        for (int hf=0;hf<4;++hf)
          af[hf] = *(const bf16x8*)(w1b + (size_t)(hf*16+lr)*256 + kt*32 + lg*8);
        #pragma unroll
        for (int tf=0;tf<4;++tf)
          bxf[tf] = *(const bf16x8*)(&xs[(tf*16+lr)*264 + kt*32 + lg*8]);
        #pragma unroll
        for (int hf=0;hf<4;++hf)
          #pragma unroll
          for (int tf=0;tf<4;++tf)
            acc1[hf][tf] = MFMA(af[hf], bxf[tf], acc1[hf][tf]);
      }
      __syncthreads();   // previous hs consumers done
      // epilogue: bias+silu, pack 4 consecutive h into hs[token][h] (one b64 write)
      #pragma unroll
      for (int hf=0;hf<4;++hf){
        int hl = wv*64 + hf*16 + lg*4;                  // h-local within half
        float4 b4 = *(const float4*)(b1g + (size_t)e*512 + hb*256 + hl);
        float bb[4] = {b4.x,b4.y,b4.z,b4.w};
        #pragma unroll
        for (int tf=0;tf<4;++tf){
          float sv[4];
          #pragma unroll
          for (int r=0;r<4;++r){
            float v = acc1[hf][tf][r] + bb[r];
            sv[r] = v/(1.f+__expf(-v));
          }
          unsigned p0 = (unsigned)f2bf(sv[0]) | ((unsigned)f2bf(sv[1])<<16);
          unsigned p1 = (unsigned)f2bf(sv[2]) | ((unsigned)f2bf(sv[3])<<16);
          *(uint2*)(&hs[(tf*16+lr)*264 + hl]) = make_uint2(p0,p1);
        }
      }
      __syncthreads();   // hs ready
      // ---- GEMM2 partial: acc2[tf][df] = hs(64x256) x w2[d-rows, h-half], no barriers ----
      f32x4 acc2[4][4];
      #pragma unroll
      for (int tf=0;tf<4;++tf)
        #pragma unroll
        for (int df=0;df<4;++df) acc2[tf][df] = (f32x4){0.f,0.f,0.f,0.f};
      const u16* w2b = w2t + ((size_t)e*256 + wv*64)*512 + hb*256;
      #pragma unroll
      for (int kt=0; kt<8; ++kt){
        bf16x8 bwf[4], ahf[4];
        #pragma unroll
        for (int df=0;df<4;++df)
          bwf[df] = *(const bf16x8*)(w2b + (size_t)(df*16+lr)*512 + kt*32 + lg*8);
        #pragma unroll
        for (int tf=0;tf<4;++tf)
          ahf[tf] = *(const bf16x8*)(&hs[(tf*16+lr)*264 + kt*32 + lg*8]);
        #pragma unroll
        for (int tf=0;tf<4;++tf)
          #pragma unroll
          for (int df=0;df<4;++df)
            acc2[tf][df] = MFMA(ahf[tf], bwf[df], acc2[tf][df]);
      }
      // fold this half into gated output accumulator
      #pragma unroll
      for (int tf=0;tf<4;++tf){
        float wv4[4];
        #pragma unroll
        for (int r=0;r<4;++r) wv4[r] = wsl[(tf*16+lg*4+r)*6 + e];
        #pragma unroll
        for (int df=0;df<4;++df){
          float b2v = (hb==0) ? b2g[e*256 + wv*64 + df*16 + lr] : 0.f;
          #pragma unroll
          for (int r=0;r<4;++r)
            oacc[tf][df][r] += wv4[r]*(acc2[tf][df][r] + b2v);
        }
      }
    }
  }
  #pragma unroll
  for (int tf=0;tf<4;++tf)
    #pragma unroll
    for (int df=0;df<4;++df)
      #pragma unroll
      for (int r=0;r<4;++r){
        int t = tb + tf*16 + lg*4 + r;
        int d = wv*64 + df*16 + lr;
        outp[(size_t)t*256+d] = xg[(size_t)t*256+d] + oacc[tf][df][r];
      }
}

extern "C" void kernel_launch(void* const* d_in, const int* in_sizes, int n_in,
                              void* d_out, int out_size, void* d_ws, size_t ws_size,
                              hipStream_t stream){
  const float* x      = (const float*)d_in[0];
  const float* regime = (const float*)d_in[1];
  const float* ln_g   = (const float*)d_in[2];
  const float* ln_b   = (const float*)d_in[3];
  const float* w1     = (const float*)d_in[4];
  const float* b1     = (const float*)d_in[5];
  const float* w2     = (const float*)d_in[6];
  const float* b2     = (const float*)d_in[7];
  const float* rw1    = (const float*)d_in[8];
  const float* rb1    = (const float*)d_in[9];
  const float* rw2    = (const float*)d_in[10];
  const float* rb2    = (const float*)d_in[11];
  float* outp = (float*)d_out;
  char* ws = (char*)d_ws;

  u16*   w1t  = (u16*)(ws + 0);          // 1,572,864
  u16*   w2t  = (u16*)(ws + 1572864);    // 1,572,864
  u16*   rwh  = (u16*)(ws + 3145728);    // 131,072
  u16*   rwl  = (u16*)(ws + 3276800);    // 131,072
  float* regb = (float*)(ws + 3407872);  // 8,192
  u16*   xh   = (u16*)(ws + 3416064);    // 16,777,216
  u16*   xl   = (u16*)(ws + 20193280);   // 16,777,216 (dead after k_router)
  float* part = (float*)(ws + 20193280); // 98,304 — overlays xl, written after router
  float* hid  = (float*)(ws + 36970496); // 33,554,432
  float* selw = (float*)(ws + 70524928); // 786,432

  k_transpose<<<384,256,0,stream>>>(w1, w2, w1t, w2t);
  k_prep_rw1<<<264,256,0,stream>>>(rw1, rb1, regime, rwh, rwl, regb);
  k_ln<<<8192,256,0,stream>>>(x, ln_g, ln_b, xh, xl);
  k_router<<<512,256,0,stream>>>(xh, xl, rwh, rwl, regb, hid);
  k_logits<<<2048,256,0,stream>>>(hid, rw2, rb2, selw, part);
  k_aux<<<1,256,0,stream>>>(part, outp);
  k_experts<<<512,256,0,stream>>>(xh, w1t, w2t, b1, b2, selw, x, outp);
}

// Round 4
// 324.283 us; speedup vs baseline: 1.7464x; 1.0256x over previous
//
#include <hip/hip_runtime.h>
#include <cmath>

typedef unsigned short u16;
typedef __attribute__((ext_vector_type(8))) short bf16x8;
typedef __attribute__((ext_vector_type(4))) float f32x4;

#define MFMA(a,b,c) __builtin_amdgcn_mfma_f32_16x16x32_bf16((a),(b),(c),0,0,0)

__device__ __forceinline__ float bf2f(u16 u){ return __uint_as_float(((unsigned)u)<<16); }
__device__ __forceinline__ u16 f2bf(float f){
  unsigned x = __float_as_uint(f);
  return (u16)((x + 0x7FFFu + ((x>>16)&1u)) >> 16);
}

// ---------- prep: LDS-tiled transpose f32 [R][C] -> bf16 [C][R] for w1 and w2 ----------
__global__ __launch_bounds__(256) void k_transpose(const float* __restrict__ w1,
        const float* __restrict__ w2, u16* __restrict__ w1t, u16* __restrict__ w2t){
  __shared__ u16 t[64][66];
  int b = blockIdx.x;
  const float* src; u16* dst; int R, C, tr, tc;
  if (b < 192){            // w1: per-expert src (D=256 x H=512) -> w1t[h][d]
    int e = b >> 5, tl = b & 31;
    R = 256; C = 512;
    src = w1 + (size_t)e*131072; dst = w1t + (size_t)e*131072;
    tr = (tl >> 3) << 6; tc = (tl & 7) << 6;
  } else {                 // w2: per-expert src (H=512 x D=256) -> w2t[d][h]
    int bb = b - 192;
    int e = bb >> 5, tl = bb & 31;
    R = 512; C = 256;
    src = w2 + (size_t)e*131072; dst = w2t + (size_t)e*131072;
    tr = (tl >> 2) << 6; tc = (tl & 3) << 6;
  }
  int c0 = threadIdx.x & 63, r0 = threadIdx.x >> 6;
  #pragma unroll
  for (int i=0;i<16;++i){
    int r = r0 + i*4;
    t[c0][r] = f2bf(src[(size_t)(tr+r)*C + tc + c0]);   // coalesced read along C
  }
  __syncthreads();
  #pragma unroll
  for (int i=0;i<16;++i){
    int cc = r0 + i*4;
    dst[(size_t)(tc+cc)*R + tr + c0] = t[cc][c0];       // coalesced write along R
  }
}

// rw1 (261,256): first 256 rows -> [j][d] hi/lo bf16; rows 256..260 + rb1 folded into regb[b][j].
__global__ void k_prep_rw1(const float* __restrict__ rw1, const float* __restrict__ rb1,
                           const float* __restrict__ regime,
                           u16* __restrict__ rwh, u16* __restrict__ rwl,
                           float* __restrict__ regb){
  int idx = blockIdx.x*256 + threadIdx.x;  // 65536 + 2048 total
  if (idx < 65536){
    int dd = idx & 255, j = idx >> 8;
    float w = rw1[dd*256 + j];
    u16 hi = f2bf(w);
    rwh[idx] = hi;
    rwl[idx] = f2bf(w - bf2f(hi));
  } else {
    int i = idx - 65536; int j = i & 255, b = i >> 8;
    float v = rb1[j];
    #pragma unroll
    for (int r=0;r<5;++r) v += regime[b*5+r]*rw1[(256+r)*256 + j];
    regb[b*256 + j] = v;
  }
}

// ---------- LayerNorm: x -> xn hi/lo bf16 (wave per token) ----------
__global__ __launch_bounds__(256) void k_ln(const float* __restrict__ x,
        const float* __restrict__ g, const float* __restrict__ bta,
        u16* __restrict__ xh, u16* __restrict__ xl){
  int wv = threadIdx.x >> 6, lane = threadIdx.x & 63;
  int t = blockIdx.x*4 + wv;
  float4 v = ((const float4*)(x + (size_t)t*256))[lane];
  float s  = v.x+v.y+v.z+v.w;
  float ss = v.x*v.x+v.y*v.y+v.z*v.z+v.w*v.w;
  #pragma unroll
  for (int m=32;m>=1;m>>=1){ s += __shfl_xor(s,m); ss += __shfl_xor(ss,m); }
  float mu  = s*(1.f/256.f);
  float var = ss*(1.f/256.f) - mu*mu;
  float inv = 1.f / sqrtf(var + 1e-5f);
  float4 gv = ((const float4*)g)[lane];
  float4 bv = ((const float4*)bta)[lane];
  float xv[4] = {v.x,v.y,v.z,v.w};
  float gg[4] = {gv.x,gv.y,gv.z,gv.w};
  float bb[4] = {bv.x,bv.y,bv.z,bv.w};
  u16 hh[4], ll[4];
  #pragma unroll
  for (int q=0;q<4;++q){
    float xn = (xv[q]-mu)*inv*gg[q] + bb[q];
    u16 h = f2bf(xn);
    hh[q] = h;
    ll[q] = f2bf(xn - bf2f(h));
  }
  ((ushort4*)(xh + (size_t)t*256))[lane] = make_ushort4(hh[0],hh[1],hh[2],hh[3]);
  ((ushort4*)(xl + (size_t)t*256))[lane] = make_ushort4(ll[0],ll[1],ll[2],ll[3]);
}

// ---------- router GEMM (hi/lo MFMA, weight frags direct from L2, no K-loop barriers) ----------
__global__ __launch_bounds__(256,2) void k_router(const u16* __restrict__ xh, const u16* __restrict__ xl,
        const u16* __restrict__ rwh, const u16* __restrict__ rwl,
        const float* __restrict__ regb, float* __restrict__ hid){
  __shared__ u16 ash[64*264];
  __shared__ u16 asl[64*264];
  int tid = threadIdx.x;
  int lane = tid & 63, wv = tid >> 6;
  int lr = lane & 15, lg = lane >> 4;
  int tb = blockIdx.x * 64;
  for (int c = tid; c < 2048; c += 256){
    int r = c >> 5, cc = c & 31;
    *(uint4*)(&ash[r*264 + cc*8]) = *(const uint4*)(xh + (size_t)(tb+r)*256 + cc*8);
    *(uint4*)(&asl[r*264 + cc*8]) = *(const uint4*)(xl + (size_t)(tb+r)*256 + cc*8);
  }
  __syncthreads();
  f32x4 acc[4][4];
  #pragma unroll
  for (int mf=0;mf<4;++mf)
    #pragma unroll
    for (int nf=0;nf<4;++nf) acc[mf][nf] = (f32x4){0.f,0.f,0.f,0.f};

  const u16* bhb = rwh + (size_t)wv*64*256;
  const u16* blb = rwl + (size_t)wv*64*256;
  #pragma unroll
  for (int kt=0;kt<8;++kt){
    bf16x8 ah[4], al[4], bh[4], bl[4];
    #pragma unroll
    for (int nf=0;nf<4;++nf){
      bh[nf] = *(const bf16x8*)(bhb + (size_t)(nf*16+lr)*256 + kt*32 + lg*8);
      bl[nf] = *(const bf16x8*)(blb + (size_t)(nf*16+lr)*256 + kt*32 + lg*8);
    }
    #pragma unroll
    for (int mf=0;mf<4;++mf){
      ah[mf] = *(const bf16x8*)(&ash[(mf*16+lr)*264 + kt*32 + lg*8]);
      al[mf] = *(const bf16x8*)(&asl[(mf*16+lr)*264 + kt*32 + lg*8]);
    }
    #pragma unroll
    for (int mf=0;mf<4;++mf)
      #pragma unroll
      for (int nf=0;nf<4;++nf){
        acc[mf][nf] = MFMA(ah[mf], bh[nf], acc[mf][nf]);
        acc[mf][nf] = MFMA(al[mf], bh[nf], acc[mf][nf]);
        acc[mf][nf] = MFMA(ah[mf], bl[nf], acc[mf][nf]);
      }
  }
  int b = tb >> 12;
  #pragma unroll
  for (int mf=0;mf<4;++mf)
    #pragma unroll
    for (int nf=0;nf<4;++nf){
      int j = wv*64 + nf*16 + lr;
      float rbv = regb[b*256 + j];
      #pragma unroll
      for (int r=0;r<4;++r){
        int t = tb + mf*16 + lg*4 + r;
        float v = acc[mf][nf][r] + rbv;
        hid[(size_t)t*256 + j] = v/(1.f+__expf(-v));
      }
    }
}

// ---------- logits + top2 + gates + aux partials (16-lane group per token, coalesced) ----------
__global__ __launch_bounds__(256) void k_logits(const float* __restrict__ hid,
        const float* __restrict__ rw2, const float* __restrict__ rb2,
        float* __restrict__ selw, float* __restrict__ partials){
  __shared__ float psum[6], pcnt[6];
  int tid = threadIdx.x;
  if (tid < 6){ psum[tid]=0.f; pcnt[tid]=0.f; }
  __syncthreads();
  int lane = tid & 63;
  int lr = lane & 15, lg = lane >> 4;
  int t = blockIdx.x*16 + (tid>>6)*4 + lg;
  float lacc[6] = {0.f,0.f,0.f,0.f,0.f,0.f};
  const float4* hp = (const float4*)(hid + (size_t)t*256);
  #pragma unroll
  for (int p=0;p<4;++p){
    float4 h4 = hp[p*16 + lr];
    float hv[4] = {h4.x,h4.y,h4.z,h4.w};
    int j0 = (p*16+lr)*4;
    #pragma unroll
    for (int q=0;q<4;++q)
      #pragma unroll
      for (int e=0;e<6;++e) lacc[e] += hv[q]*rw2[(j0+q)*6+e];
  }
  #pragma unroll
  for (int m=1;m<16;m<<=1)
    #pragma unroll
    for (int e=0;e<6;++e) lacc[e] += __shfl_xor(lacc[e], m);
  if (lr == 0){
    float lgv[6];
    #pragma unroll
    for (int e=0;e<6;++e) lgv[e] = lacc[e] + rb2[e];
    int i0=0; float v0=lgv[0];
    #pragma unroll
    for (int e=1;e<6;++e) if (lgv[e] > v0){ v0=lgv[e]; i0=e; }
    int i1=-1; float v1=-1e30f;
    #pragma unroll
    for (int e=0;e<6;++e) if (e!=i0 && lgv[e] > v1){ v1=lgv[e]; i1=e; }
    float ex = expf(v1-v0);
    float w0 = 1.f/(1.f+ex), w1 = ex/(1.f+ex);
    #pragma unroll
    for (int e=0;e<6;++e) selw[(size_t)t*6+e] = (e==i0)? w0 : (e==i1)? w1 : 0.f;
    float ps=0.f, p[6];
    #pragma unroll
    for (int e=0;e<6;++e){ p[e]=expf(lgv[e]-v0); ps+=p[e]; }
    float rinv = 1.f/ps;
    #pragma unroll
    for (int e=0;e<6;++e) atomicAdd(&psum[e], p[e]*rinv);
    atomicAdd(&pcnt[i0], 1.f);
  }
  __syncthreads();
  if (tid < 6){
    partials[blockIdx.x*12 + tid] = psum[tid];
    partials[blockIdx.x*12 + 6 + tid] = pcnt[tid];
  }
}

__global__ __launch_bounds__(256) void k_aux(const float* __restrict__ partials, float* __restrict__ outp){
  __shared__ float a[12];
  int tid = threadIdx.x;
  if (tid < 12) a[tid] = 0.f;
  __syncthreads();
  int col = tid & 15, seg = tid >> 4;
  if (col < 12){
    float s = 0.f;
    for (int i=seg; i<2048; i+=16) s += partials[i*12+col];
    atomicAdd(&a[col], s);
  }
  __syncthreads();
  if (tid==0){
    float aux=0.f;
    #pragma unroll
    for (int e=0;e<6;++e) aux += a[e]*a[6+e];
    aux *= 0.01f*6.f/(32768.f*32768.f);
    outp[8388608] = aux;
  }
}

// ---------- fused all-expert MLP: 8 waves, 32-wide N-slices, prefetched weight frags ----------
__global__ __launch_bounds__(512,4) void k_experts(const u16* __restrict__ xh,
        const u16* __restrict__ w1t, const u16* __restrict__ w2t,
        const float* __restrict__ b1g, const float* __restrict__ b2g,
        const float* __restrict__ selw, const float* __restrict__ xg,
        float* __restrict__ outp){
  __shared__ u16 xs[64*264];
  __shared__ u16 hs[64*264];
  __shared__ float wsl[64*6];
  int tid = threadIdx.x;                    // 512 threads = 8 waves
  int lane = tid & 63, wv = tid >> 6;       // wv 0..7
  int lr = lane & 15, lg = lane >> 4;
  int tb = blockIdx.x * 64;

  for (int c = tid; c < 2048; c += 512){
    int r = c >> 5, cc = c & 31;
    *(uint4*)(&xs[r*264 + cc*8]) = *(const uint4*)(xh + (size_t)(tb+r)*256 + cc*8);
  }
  if (tid < 384) wsl[tid] = selw[(size_t)tb*6 + tid];
  __syncthreads();

  f32x4 oacc[4][2];                          // [token-frag][d-frag] — wave owns 32 d
  #pragma unroll
  for (int tf=0;tf<4;++tf)
    #pragma unroll
    for (int df=0;df<2;++df) oacc[tf][df] = (f32x4){0.f,0.f,0.f,0.f};

  for (int e=0;e<6;++e){
    #pragma unroll
    for (int hb=0; hb<2; ++hb){
      // ---- GEMM1 swapped: wave owns 32 h-rows of this half; K=256, no barriers ----
      f32x4 acc1[2][4];
      #pragma unroll
      for (int hf=0;hf<2;++hf)
        #pragma unroll
        for (int tf=0;tf<4;++tf) acc1[hf][tf] = (f32x4){0.f,0.f,0.f,0.f};
      const u16* w1b = w1t + ((size_t)(e*512 + hb*256 + wv*32))*256;
      bf16x8 afp0 = *(const bf16x8*)(w1b + (size_t)lr*256 + lg*8);
      bf16x8 afp1 = *(const bf16x8*)(w1b + (size_t)(16+lr)*256 + lg*8);
      #pragma unroll
      for (int kt=0; kt<8; ++kt){
        bf16x8 af0 = afp0, af1 = afp1;
        if (kt < 7){
          afp0 = *(const bf16x8*)(w1b + (size_t)lr*256 + (kt+1)*32 + lg*8);
          afp1 = *(const bf16x8*)(w1b + (size_t)(16+lr)*256 + (kt+1)*32 + lg*8);
        }
        bf16x8 bxf[4];
        #pragma unroll
        for (int tf=0;tf<4;++tf)
          bxf[tf] = *(const bf16x8*)(&xs[(tf*16+lr)*264 + kt*32 + lg*8]);
        #pragma unroll
        for (int tf=0;tf<4;++tf){
          acc1[0][tf] = MFMA(af0, bxf[tf], acc1[0][tf]);
          acc1[1][tf] = MFMA(af1, bxf[tf], acc1[1][tf]);
        }
      }
      __syncthreads();   // previous hs consumers done
      // epilogue: bias+silu, pack 4 consecutive h into hs[token][h] (one b64 write)
      #pragma unroll
      for (int hf=0;hf<2;++hf){
        int hl = wv*32 + hf*16 + lg*4;                  // h-local within half (0..255)
        float4 b4 = *(const float4*)(b1g + (size_t)e*512 + hb*256 + hl);
        float bb[4] = {b4.x,b4.y,b4.z,b4.w};
        #pragma unroll
        for (int tf=0;tf<4;++tf){
          float sv[4];
          #pragma unroll
          for (int r=0;r<4;++r){
            float v = acc1[hf][tf][r] + bb[r];
            sv[r] = v/(1.f+__expf(-v));
          }
          unsigned p0 = (unsigned)f2bf(sv[0]) | ((unsigned)f2bf(sv[1])<<16);
          unsigned p1 = (unsigned)f2bf(sv[2]) | ((unsigned)f2bf(sv[3])<<16);
          *(uint2*)(&hs[(tf*16+lr)*264 + hl]) = make_uint2(p0,p1);
        }
      }
      __syncthreads();   // hs ready
      // ---- GEMM2 partial: wave owns 32 d-rows; K=256 (this h-half), no barriers ----
      f32x4 acc2[4][2];
      #pragma unroll
      for (int tf=0;tf<4;++tf)
        #pragma unroll
        for (int df=0;df<2;++df) acc2[tf][df] = (f32x4){0.f,0.f,0.f,0.f};
      const u16* w2b = w2t + ((size_t)(e*256 + wv*32))*512 + hb*256;
      bf16x8 bwp0 = *(const bf16x8*)(w2b + (size_t)lr*512 + lg*8);
      bf16x8 bwp1 = *(const bf16x8*)(w2b + (size_t)(16+lr)*512 + lg*8);
      #pragma unroll
      for (int kt=0; kt<8; ++kt){
        bf16x8 bw0 = bwp0, bw1 = bwp1;
        if (kt < 7){
          bwp0 = *(const bf16x8*)(w2b + (size_t)lr*512 + (kt+1)*32 + lg*8);
          bwp1 = *(const bf16x8*)(w2b + (size_t)(16+lr)*512 + (kt+1)*32 + lg*8);
        }
        bf16x8 ahf[4];
        #pragma unroll
        for (int tf=0;tf<4;++tf)
          ahf[tf] = *(const bf16x8*)(&hs[(tf*16+lr)*264 + kt*32 + lg*8]);
        #pragma unroll
        for (int tf=0;tf<4;++tf){
          acc2[tf][0] = MFMA(ahf[tf], bw0, acc2[tf][0]);
          acc2[tf][1] = MFMA(ahf[tf], bw1, acc2[tf][1]);
        }
      }
      // fold this half into gated output accumulator
      #pragma unroll
      for (int tf=0;tf<4;++tf){
        float wv4[4];
        #pragma unroll
        for (int r=0;r<4;++r) wv4[r] = wsl[(tf*16+lg*4+r)*6 + e];
        #pragma unroll
        for (int df=0;df<2;++df){
          float b2v = (hb==0) ? b2g[e*256 + wv*32 + df*16 + lr] : 0.f;
          #pragma unroll
          for (int r=0;r<4;++r)
            oacc[tf][df][r] += wv4[r]*(acc2[tf][df][r] + b2v);
        }
      }
    }
  }
  #pragma unroll
  for (int tf=0;tf<4;++tf)
    #pragma unroll
    for (int df=0;df<2;++df)
      #pragma unroll
      for (int r=0;r<4;++r){
        int t = tb + tf*16 + lg*4 + r;
        int d = wv*32 + df*16 + lr;
        outp[(size_t)t*256+d] = xg[(size_t)t*256+d] + oacc[tf][df][r];
      }
}

extern "C" void kernel_launch(void* const* d_in, const int* in_sizes, int n_in,
                              void* d_out, int out_size, void* d_ws, size_t ws_size,
                              hipStream_t stream){
  const float* x      = (const float*)d_in[0];
  const float* regime = (const float*)d_in[1];
  const float* ln_g   = (const float*)d_in[2];
  const float* ln_b   = (const float*)d_in[3];
  const float* w1     = (const float*)d_in[4];
  const float* b1     = (const float*)d_in[5];
  const float* w2     = (const float*)d_in[6];
  const float* b2     = (const float*)d_in[7];
  const float* rw1    = (const float*)d_in[8];
  const float* rb1    = (const float*)d_in[9];
  const float* rw2    = (const float*)d_in[10];
  const float* rb2    = (const float*)d_in[11];
  float* outp = (float*)d_out;
  char* ws = (char*)d_ws;

  u16*   w1t  = (u16*)(ws + 0);          // 1,572,864
  u16*   w2t  = (u16*)(ws + 1572864);    // 1,572,864
  u16*   rwh  = (u16*)(ws + 3145728);    // 131,072
  u16*   rwl  = (u16*)(ws + 3276800);    // 131,072
  float* regb = (float*)(ws + 3407872);  // 8,192
  u16*   xh   = (u16*)(ws + 3416064);    // 16,777,216
  u16*   xl   = (u16*)(ws + 20193280);   // 16,777,216 (dead after k_router)
  float* part = (float*)(ws + 20193280); // 98,304 — overlays xl, written after router
  float* hid  = (float*)(ws + 36970496); // 33,554,432
  float* selw = (float*)(ws + 70524928); // 786,432

  k_transpose<<<384,256,0,stream>>>(w1, w2, w1t, w2t);
  k_prep_rw1<<<264,256,0,stream>>>(rw1, rb1, regime, rwh, rwl, regb);
  k_ln<<<8192,256,0,stream>>>(x, ln_g, ln_b, xh, xl);
  k_router<<<512,256,0,stream>>>(xh, xl, rwh, rwl, regb, hid);
  k_logits<<<2048,256,0,stream>>>(hid, rw2, rb2, selw, part);
  k_aux<<<1,256,0,stream>>>(part, outp);
  k_experts<<<512,512,0,stream>>>(xh, w1t, w2t, b1, b2, selw, x, outp);
}

// Round 5
// 293.047 us; speedup vs baseline: 1.9325x; 1.1066x over previous
//
#include <hip/hip_runtime.h>
#include <cmath>

typedef unsigned short u16;
typedef __attribute__((ext_vector_type(8))) short bf16x8;
typedef __attribute__((ext_vector_type(4))) float f32x4;

#define MFMA(a,b,c) __builtin_amdgcn_mfma_f32_16x16x32_bf16((a),(b),(c),0,0,0)

__device__ __forceinline__ float bf2f(u16 u){ return __uint_as_float(((unsigned)u)<<16); }
__device__ __forceinline__ u16 f2bf(float f){
  unsigned x = __float_as_uint(f);
  return (u16)((x + 0x7FFFu + ((x>>16)&1u)) >> 16);
}

__device__ __forceinline__ void gll16(const u16* g, u16* l){
  __builtin_amdgcn_global_load_lds((const __attribute__((address_space(1))) unsigned*)g,
                                   (__attribute__((address_space(3))) unsigned*)l, 16, 0, 0);
}

// ---------- prep: LDS-tiled transpose f32 [R][C] -> bf16 [C][R] for w1 and w2 ----------
__global__ __launch_bounds__(256) void k_transpose(const float* __restrict__ w1,
        const float* __restrict__ w2, u16* __restrict__ w1t, u16* __restrict__ w2t){
  __shared__ u16 t[64][66];
  int b = blockIdx.x;
  const float* src; u16* dst; int R, C, tr, tc;
  if (b < 192){            // w1: per-expert src (D=256 x H=512) -> w1t[h][d]
    int e = b >> 5, tl = b & 31;
    R = 256; C = 512;
    src = w1 + (size_t)e*131072; dst = w1t + (size_t)e*131072;
    tr = (tl >> 3) << 6; tc = (tl & 7) << 6;
  } else {                 // w2: per-expert src (H=512 x D=256) -> w2t[d][h]
    int bb = b - 192;
    int e = bb >> 5, tl = bb & 31;
    R = 512; C = 256;
    src = w2 + (size_t)e*131072; dst = w2t + (size_t)e*131072;
    tr = (tl >> 2) << 6; tc = (tl & 3) << 6;
  }
  int c0 = threadIdx.x & 63, r0 = threadIdx.x >> 6;
  #pragma unroll
  for (int i=0;i<16;++i){
    int r = r0 + i*4;
    t[c0][r] = f2bf(src[(size_t)(tr+r)*C + tc + c0]);
  }
  __syncthreads();
  #pragma unroll
  for (int i=0;i<16;++i){
    int cc = r0 + i*4;
    dst[(size_t)(tc+cc)*R + tr + c0] = t[cc][c0];
  }
}

// rw1 (261,256): first 256 rows -> [j][d] hi/lo bf16; rows 256..260 + rb1 folded into regb[b][j].
__global__ void k_prep_rw1(const float* __restrict__ rw1, const float* __restrict__ rb1,
                           const float* __restrict__ regime,
                           u16* __restrict__ rwh, u16* __restrict__ rwl,
                           float* __restrict__ regb){
  int idx = blockIdx.x*256 + threadIdx.x;  // 65536 + 2048 total
  if (idx < 65536){
    int dd = idx & 255, j = idx >> 8;
    float w = rw1[dd*256 + j];
    u16 hi = f2bf(w);
    rwh[idx] = hi;
    rwl[idx] = f2bf(w - bf2f(hi));
  } else {
    int i = idx - 65536; int j = i & 255, b = i >> 8;
    float v = rb1[j];
    #pragma unroll
    for (int r=0;r<5;++r) v += regime[b*5+r]*rw1[(256+r)*256 + j];
    regb[b*256 + j] = v;
  }
}

// ---------- LayerNorm: x -> xn hi/lo bf16 (wave per token) ----------
__global__ __launch_bounds__(256) void k_ln(const float* __restrict__ x,
        const float* __restrict__ g, const float* __restrict__ bta,
        u16* __restrict__ xh, u16* __restrict__ xl){
  int wv = threadIdx.x >> 6, lane = threadIdx.x & 63;
  int t = blockIdx.x*4 + wv;
  float4 v = ((const float4*)(x + (size_t)t*256))[lane];
  float s  = v.x+v.y+v.z+v.w;
  float ss = v.x*v.x+v.y*v.y+v.z*v.z+v.w*v.w;
  #pragma unroll
  for (int m=32;m>=1;m>>=1){ s += __shfl_xor(s,m); ss += __shfl_xor(ss,m); }
  float mu  = s*(1.f/256.f);
  float var = ss*(1.f/256.f) - mu*mu;
  float inv = 1.f / sqrtf(var + 1e-5f);
  float4 gv = ((const float4*)g)[lane];
  float4 bv = ((const float4*)bta)[lane];
  float xv[4] = {v.x,v.y,v.z,v.w};
  float gg[4] = {gv.x,gv.y,gv.z,gv.w};
  float bb[4] = {bv.x,bv.y,bv.z,bv.w};
  u16 hh[4], ll[4];
  #pragma unroll
  for (int q=0;q<4;++q){
    float xn = (xv[q]-mu)*inv*gg[q] + bb[q];
    u16 h = f2bf(xn);
    hh[q] = h;
    ll[q] = f2bf(xn - bf2f(h));
  }
  ((ushort4*)(xh + (size_t)t*256))[lane] = make_ushort4(hh[0],hh[1],hh[2],hh[3]);
  ((ushort4*)(xl + (size_t)t*256))[lane] = make_ushort4(ll[0],ll[1],ll[2],ll[3]);
}

// ---------- router GEMM (hi/lo MFMA, weight frags direct from L2) ----------
__global__ __launch_bounds__(256,2) void k_router(const u16* __restrict__ xh, const u16* __restrict__ xl,
        const u16* __restrict__ rwh, const u16* __restrict__ rwl,
        const float* __restrict__ regb, float* __restrict__ hid){
  __shared__ u16 ash[64*264];
  __shared__ u16 asl[64*264];
  int tid = threadIdx.x;
  int lane = tid & 63, wv = tid >> 6;
  int lr = lane & 15, lg = lane >> 4;
  int tb = blockIdx.x * 64;
  for (int c = tid; c < 2048; c += 256){
    int r = c >> 5, cc = c & 31;
    *(uint4*)(&ash[r*264 + cc*8]) = *(const uint4*)(xh + (size_t)(tb+r)*256 + cc*8);
    *(uint4*)(&asl[r*264 + cc*8]) = *(const uint4*)(xl + (size_t)(tb+r)*256 + cc*8);
  }
  __syncthreads();
  f32x4 acc[4][4];
  #pragma unroll
  for (int mf=0;mf<4;++mf)
    #pragma unroll
    for (int nf=0;nf<4;++nf) acc[mf][nf] = (f32x4){0.f,0.f,0.f,0.f};

  const u16* bhb = rwh + (size_t)wv*64*256;
  const u16* blb = rwl + (size_t)wv*64*256;
  #pragma unroll
  for (int kt=0;kt<8;++kt){
    bf16x8 ah[4], al[4], bh[4], bl[4];
    #pragma unroll
    for (int nf=0;nf<4;++nf){
      bh[nf] = *(const bf16x8*)(bhb + (size_t)(nf*16+lr)*256 + kt*32 + lg*8);
      bl[nf] = *(const bf16x8*)(blb + (size_t)(nf*16+lr)*256 + kt*32 + lg*8);
    }
    #pragma unroll
    for (int mf=0;mf<4;++mf){
      ah[mf] = *(const bf16x8*)(&ash[(mf*16+lr)*264 + kt*32 + lg*8]);
      al[mf] = *(const bf16x8*)(&asl[(mf*16+lr)*264 + kt*32 + lg*8]);
    }
    #pragma unroll
    for (int mf=0;mf<4;++mf)
      #pragma unroll
      for (int nf=0;nf<4;++nf){
        acc[mf][nf] = MFMA(ah[mf], bh[nf], acc[mf][nf]);
        acc[mf][nf] = MFMA(al[mf], bh[nf], acc[mf][nf]);
        acc[mf][nf] = MFMA(ah[mf], bl[nf], acc[mf][nf]);
      }
  }
  int b = tb >> 12;
  #pragma unroll
  for (int mf=0;mf<4;++mf)
    #pragma unroll
    for (int nf=0;nf<4;++nf){
      int j = wv*64 + nf*16 + lr;
      float rbv = regb[b*256 + j];
      #pragma unroll
      for (int r=0;r<4;++r){
        int t = tb + mf*16 + lg*4 + r;
        float v = acc[mf][nf][r] + rbv;
        hid[(size_t)t*256 + j] = v/(1.f+__expf(-v));
      }
    }
}

// ---------- logits + top2 + gates + aux partials (16-lane group per token, coalesced) ----------
__global__ __launch_bounds__(256) void k_logits(const float* __restrict__ hid,
        const float* __restrict__ rw2, const float* __restrict__ rb2,
        float* __restrict__ selw, float* __restrict__ partials){
  __shared__ float psum[6], pcnt[6];
  int tid = threadIdx.x;
  if (tid < 6){ psum[tid]=0.f; pcnt[tid]=0.f; }
  __syncthreads();
  int lane = tid & 63;
  int lr = lane & 15, lg = lane >> 4;
  int t = blockIdx.x*16 + (tid>>6)*4 + lg;
  float lacc[6] = {0.f,0.f,0.f,0.f,0.f,0.f};
  const float4* hp = (const float4*)(hid + (size_t)t*256);
  #pragma unroll
  for (int p=0;p<4;++p){
    float4 h4 = hp[p*16 + lr];
    float hv[4] = {h4.x,h4.y,h4.z,h4.w};
    int j0 = (p*16+lr)*4;
    #pragma unroll
    for (int q=0;q<4;++q)
      #pragma unroll
      for (int e=0;e<6;++e) lacc[e] += hv[q]*rw2[(j0+q)*6+e];
  }
  #pragma unroll
  for (int m=1;m<16;m<<=1)
    #pragma unroll
    for (int e=0;e<6;++e) lacc[e] += __shfl_xor(lacc[e], m);
  if (lr == 0){
    float lgv[6];
    #pragma unroll
    for (int e=0;e<6;++e) lgv[e] = lacc[e] + rb2[e];
    int i0=0; float v0=lgv[0];
    #pragma unroll
    for (int e=1;e<6;++e) if (lgv[e] > v0){ v0=lgv[e]; i0=e; }
    int i1=-1; float v1=-1e30f;
    #pragma unroll
    for (int e=0;e<6;++e) if (e!=i0 && lgv[e] > v1){ v1=lgv[e]; i1=e; }
    float ex = expf(v1-v0);
    float w0 = 1.f/(1.f+ex), w1 = ex/(1.f+ex);
    #pragma unroll
    for (int e=0;e<6;++e) selw[(size_t)t*6+e] = (e==i0)? w0 : (e==i1)? w1 : 0.f;
    float ps=0.f, p[6];
    #pragma unroll
    for (int e=0;e<6;++e){ p[e]=expf(lgv[e]-v0); ps+=p[e]; }
    float rinv = 1.f/ps;
    #pragma unroll
    for (int e=0;e<6;++e) atomicAdd(&psum[e], p[e]*rinv);
    atomicAdd(&pcnt[i0], 1.f);
  }
  __syncthreads();
  if (tid < 6){
    partials[blockIdx.x*12 + tid] = psum[tid];
    partials[blockIdx.x*12 + 6 + tid] = pcnt[tid];
  }
}

__global__ __launch_bounds__(256) void k_aux(const float* __restrict__ partials, float* __restrict__ outp){
  __shared__ float a[12];
  int tid = threadIdx.x;
  if (tid < 12) a[tid] = 0.f;
  __syncthreads();
  int col = tid & 15, seg = tid >> 4;
  if (col < 12){
    float s = 0.f;
    for (int i=seg; i<2048; i+=16) s += partials[i*12+col];
    atomicAdd(&a[col], s);
  }
  __syncthreads();
  if (tid==0){
    float aux=0.f;
    #pragma unroll
    for (int e=0;e<6;++e) aux += a[e]*a[6+e];
    aux *= 0.01f*6.f/(32768.f*32768.f);
    outp[8388608] = aux;
  }
}

// ---------- fused all-expert MLP v3: coalesced LDS weight staging, 128-token tiles ----------
// LDS map (u16 units): xs [0,32768)  hs [32768,49152)  wt0 [49152,57344)  wt1 [57344,65536)
//                      wsl (float) at 65536 (768 floats)
// chunk schedule: ci = 0..191; e=ci>>5, q=(ci>>3)&3, w=ci&7 (w<4: G1 kt-pair w; else G2 kt w-4)
__device__ __forceinline__ void stage_chunk(int ci, u16* lds,
        const u16* __restrict__ w1t, const u16* __restrict__ w2t, int wv, int lane){
  int e = ci>>5, q = (ci>>3)&3, w = ci&7;
  int base = 49152 + (ci&1)*8192;
  if (w < 4){                       // G1: 128 h-rows x 64 d (rows 128B, 8 slots), swz ^(row&7)
    #pragma unroll
    for (int j=0;j<2;++j){
      int row = j*64 + wv*8 + (lane>>3);
      int ss = (lane&7) ^ (row&7);
      const u16* src = w1t + (size_t)e*131072 + (size_t)(q*128+row)*256 + w*64 + ss*8;
      gll16(src, lds + base + j*4096 + wv*512);
    }
  } else {                          // G2: 256 d-rows x 32 h (rows 64B, 4 slots), swz ^((row>>1)&3)
    #pragma unroll
    for (int j=0;j<2;++j){
      int row = j*128 + wv*16 + (lane>>2);
      int ss = (lane&3) ^ ((row>>1)&3);
      const u16* src = w2t + (size_t)e*131072 + (size_t)row*512 + q*128 + (w-4)*32 + ss*8;
      gll16(src, lds + base + j*4096 + wv*512);
    }
  }
}

__global__ __launch_bounds__(512,2) void k_experts(const u16* __restrict__ xh,
        const u16* __restrict__ w1t, const u16* __restrict__ w2t,
        const float* __restrict__ b1g, const float* __restrict__ b2g,
        const float* __restrict__ selw, const float* __restrict__ xg,
        float* __restrict__ outp){
  __shared__ u16 lds[67072];
  int tid = threadIdx.x;                    // 512 threads = 8 waves
  int lane = tid & 63, wv = tid >> 6;
  int lr = lane & 15, lg = lane >> 4;
  int tb = blockIdx.x * 128;
  float* wsl = (float*)&lds[65536];

  // prologue: stage xs (128 tokens x 256 d, rows 512B/32 slots, swz ^(row&7)) + chunk 0 + gates
  #pragma unroll
  for (int j=0;j<8;++j){
    int row = j*16 + wv*2 + (lane>>5);
    int ss = (lane&31) ^ (row&7);
    gll16(xh + (size_t)(tb+row)*256 + ss*8, lds + j*4096 + wv*512);
  }
  stage_chunk(0, lds, w1t, w2t, wv, lane);
  for (int i=tid;i<768;i+=512) wsl[i] = selw[(size_t)tb*6 + i];
  __syncthreads();

  f32x4 oacc[8][2];
  #pragma unroll
  for (int tf=0;tf<8;++tf){ oacc[tf][0]=(f32x4){0,0,0,0}; oacc[tf][1]=(f32x4){0,0,0,0}; }

  int ci = 0;
  for (int e=0;e<6;++e){
    f32x4 acc2[8][2];
    #pragma unroll
    for (int tf=0;tf<8;++tf){ acc2[tf][0]=(f32x4){0,0,0,0}; acc2[tf][1]=(f32x4){0,0,0,0}; }
    for (int q=0;q<4;++q){
      f32x4 acc1[8];
      #pragma unroll
      for (int tf=0;tf<8;++tf) acc1[tf]=(f32x4){0,0,0,0};
      // ---- GEMM1: 4 phases (kt-pairs), wave owns 16 h-rows ----
      for (int c=0;c<4;++c){
        if (ci+1 < 192) stage_chunk(ci+1, lds, w1t, w2t, wv, lane);
        int wb = 49152 + (ci&1)*8192;
        int hr = wv*16 + lr;
        #pragma unroll
        for (int k2=0;k2<2;++k2){
          bf16x8 af = *(const bf16x8*)&lds[wb + hr*64 + (((k2*4+lg)^(hr&7))*8)];
          #pragma unroll
          for (int tf=0;tf<8;++tf){
            bf16x8 bx = *(const bf16x8*)&lds[(tf*16+lr)*256 + ((((c*2+k2)*4+lg)^(lr&7))*8)];
            acc1[tf] = MFMA(af, bx, acc1[tf]);
          }
        }
        __syncthreads();
        ++ci;
      }
      // ---- hs epilogue: bias+silu, swizzled 8B packs ----
      {
        int hl4 = wv*16 + lg*4;
        float4 b4 = *(const float4*)(b1g + (size_t)e*512 + q*128 + hl4);
        float bb[4] = {b4.x,b4.y,b4.z,b4.w};
        int sl0 = 2*wv + (lg>>1);
        #pragma unroll
        for (int tf=0;tf<8;++tf){
          float sv[4];
          #pragma unroll
          for (int r=0;r<4;++r){
            float v = acc1[tf][r] + bb[r];
            sv[r] = v/(1.f+__expf(-v));
          }
          unsigned p0 = (unsigned)f2bf(sv[0]) | ((unsigned)f2bf(sv[1])<<16);
          unsigned p1 = (unsigned)f2bf(sv[2]) | ((unsigned)f2bf(sv[3])<<16);
          int row = tf*16 + lr;
          *(uint2*)&lds[32768 + row*128 + ((sl0^(row&7))*8) + (lg&1)*4] = make_uint2(p0,p1);
        }
      }
      __syncthreads();
      // ---- GEMM2: 4 phases (kt over this h-quarter), wave owns 32 d-rows ----
      for (int c=0;c<4;++c){
        if (ci+1 < 192) stage_chunk(ci+1, lds, w1t, w2t, wv, lane);
        int wb = 49152 + (ci&1)*8192;
        int dr0 = wv*32 + lr, dr1 = wv*32 + 16 + lr;
        bf16x8 bw0 = *(const bf16x8*)&lds[wb + dr0*32 + ((lg^((dr0>>1)&3))*8)];
        bf16x8 bw1 = *(const bf16x8*)&lds[wb + dr1*32 + ((lg^((dr1>>1)&3))*8)];
        #pragma unroll
        for (int tf=0;tf<8;++tf){
          bf16x8 ah = *(const bf16x8*)&lds[32768 + (tf*16+lr)*128 + (((c*4+lg)^(lr&7))*8)];
          acc2[tf][0] = MFMA(ah, bw0, acc2[tf][0]);
          acc2[tf][1] = MFMA(ah, bw1, acc2[tf][1]);
        }
        __syncthreads();
        ++ci;
      }
    }
    // ---- fold expert e into gated output accumulator ----
    #pragma unroll
    for (int tf=0;tf<8;++tf){
      float g4[4];
      #pragma unroll
      for (int r=0;r<4;++r) g4[r] = wsl[(tf*16+lg*4+r)*6 + e];
      #pragma unroll
      for (int df=0;df<2;++df){
        float b2v = b2g[e*256 + wv*32 + df*16 + lr];
        #pragma unroll
        for (int r=0;r<4;++r)
          oacc[tf][df][r] += g4[r]*(acc2[tf][df][r] + b2v);
      }
    }
  }
  // ---- residual + store ----
  #pragma unroll
  for (int tf=0;tf<8;++tf)
    #pragma unroll
    for (int df=0;df<2;++df)
      #pragma unroll
      for (int r=0;r<4;++r){
        int t = tb + tf*16 + lg*4 + r;
        int d = wv*32 + df*16 + lr;
        outp[(size_t)t*256+d] = xg[(size_t)t*256+d] + oacc[tf][df][r];
      }
}

extern "C" void kernel_launch(void* const* d_in, const int* in_sizes, int n_in,
                              void* d_out, int out_size, void* d_ws, size_t ws_size,
                              hipStream_t stream){
  const float* x      = (const float*)d_in[0];
  const float* regime = (const float*)d_in[1];
  const float* ln_g   = (const float*)d_in[2];
  const float* ln_b   = (const float*)d_in[3];
  const float* w1     = (const float*)d_in[4];
  const float* b1     = (const float*)d_in[5];
  const float* w2     = (const float*)d_in[6];
  const float* b2     = (const float*)d_in[7];
  const float* rw1    = (const float*)d_in[8];
  const float* rb1    = (const float*)d_in[9];
  const float* rw2    = (const float*)d_in[10];
  const float* rb2    = (const float*)d_in[11];
  float* outp = (float*)d_out;
  char* ws = (char*)d_ws;

  u16*   w1t  = (u16*)(ws + 0);          // 1,572,864
  u16*   w2t  = (u16*)(ws + 1572864);    // 1,572,864
  u16*   rwh  = (u16*)(ws + 3145728);    // 131,072
  u16*   rwl  = (u16*)(ws + 3276800);    // 131,072
  float* regb = (float*)(ws + 3407872);  // 8,192
  u16*   xh   = (u16*)(ws + 3416064);    // 16,777,216
  u16*   xl   = (u16*)(ws + 20193280);   // 16,777,216 (dead after k_router)
  float* part = (float*)(ws + 20193280); // 98,304 — overlays xl, written after router
  float* hid  = (float*)(ws + 36970496); // 33,554,432
  float* selw = (float*)(ws + 70524928); // 786,432

  k_transpose<<<384,256,0,stream>>>(w1, w2, w1t, w2t);
  k_prep_rw1<<<264,256,0,stream>>>(rw1, rb1, regime, rwh, rwl, regb);
  k_ln<<<8192,256,0,stream>>>(x, ln_g, ln_b, xh, xl);
  k_router<<<512,256,0,stream>>>(xh, xl, rwh, rwl, regb, hid);
  k_logits<<<2048,256,0,stream>>>(hid, rw2, rb2, selw, part);
  k_aux<<<1,256,0,stream>>>(part, outp);
  k_experts<<<256,512,0,stream>>>(xh, w1t, w2t, b1, b2, selw, x, outp);
}